// Round 1
// baseline (8807.497 us; speedup 1.0000x reference)
//
#include <hip/hip_runtime.h>

#define NN      524288      // nodes
#define NE      2097152     // edges
#define NGRAPH  16384
#define GSZ     32
#define PADR    45
#define F_IN    79
#define F_MID   138
#define F_OUT   128

// ---------------- degree / CSR build ----------------

__global__ void k_init_cnt(int* __restrict__ cnt) {
    int i = blockIdx.x * 256 + threadIdx.x;
    if (i < NN) cnt[i] = 1;                      // self loop
}

__global__ void k_count(const int* __restrict__ dst, int* __restrict__ cnt) {
    int e = blockIdx.x * 256 + threadIdx.x;
    if (e < NE) atomicAdd(&cnt[dst[e]], 1);
}

// block scans 1024 elems (256 thr x 4); writes per-elem exclusive (local) + block sum
__global__ void k_scan1(const int* __restrict__ cnt, int* __restrict__ rp,
                        int* __restrict__ bsum) {
    __shared__ int s[256];
    int tid = threadIdx.x;
    size_t base = (size_t)blockIdx.x * 1024 + (size_t)tid * 4;
    int c0 = cnt[base + 0], c1 = cnt[base + 1], c2 = cnt[base + 2], c3 = cnt[base + 3];
    int tsum = c0 + c1 + c2 + c3;
    s[tid] = tsum;
    __syncthreads();
    for (int off = 1; off < 256; off <<= 1) {
        int t = (tid >= off) ? s[tid - off] : 0;
        __syncthreads();
        s[tid] += t;
        __syncthreads();
    }
    int incl = s[tid];
    int ex = incl - tsum;
    rp[base + 0] = ex;
    rp[base + 1] = ex + c0;
    rp[base + 2] = ex + c0 + c1;
    rp[base + 3] = ex + c0 + c1 + c2;
    if (tid == 255) bsum[blockIdx.x] = incl;
}

// single block, 512 threads: exclusive scan of the 512 block sums
__global__ void k_scan2(int* __restrict__ bsum) {
    __shared__ int s[512];
    int tid = threadIdx.x;
    int v = bsum[tid];
    s[tid] = v;
    __syncthreads();
    for (int off = 1; off < 512; off <<= 1) {
        int t = (tid >= off) ? s[tid - off] : 0;
        __syncthreads();
        s[tid] += t;
        __syncthreads();
    }
    bsum[tid] = s[tid] - v;                      // exclusive
}

__global__ void k_scan3(int* __restrict__ rp, const int* __restrict__ bsum,
                        int* __restrict__ cursor) {
    int i = blockIdx.x * 256 + threadIdx.x;
    if (i < NN) {
        int v = rp[i] + bsum[i >> 10];
        rp[i] = v;
        cursor[i] = v;
        if (i == 0) rp[NN] = NN + NE;
    }
}

__global__ void k_dinv(const int* __restrict__ cnt, float* __restrict__ dinv) {
    int i = blockIdx.x * 256 + threadIdx.x;
    if (i < NN) dinv[i] = rsqrtf((float)cnt[i]);
}

__global__ void k_fill_self(int* __restrict__ cursor, int* __restrict__ col) {
    int i = blockIdx.x * 256 + threadIdx.x;
    if (i < NN) { int s = atomicAdd(&cursor[i], 1); col[s] = i; }
}

__global__ void k_fill_edges(const int* __restrict__ src, const int* __restrict__ dst,
                             int* __restrict__ cursor, int* __restrict__ col) {
    int e = blockIdx.x * 256 + threadIdx.x;
    if (e < NE) { int s = atomicAdd(&cursor[dst[e]], 1); col[s] = src[e]; }
}

// ---------------- aggregation: out[i] = dinv[i] * sum_j dinv[j] * h[j] ----------------
// one wave (64 lanes) per node; lanes cover dims {lane, lane+64, lane+128}
__global__ void k_agg(const float* __restrict__ hin, float* __restrict__ hout,
                      const int* __restrict__ rp, const int* __restrict__ col,
                      const float* __restrict__ dinv, int D) {
    int gid  = blockIdx.x * blockDim.x + threadIdx.x;
    int node = gid >> 6;
    int lane = threadIdx.x & 63;
    if (node >= NN) return;
    int beg = rp[node], end = rp[node + 1];
    float a0 = 0.f, a1 = 0.f, a2 = 0.f;
    for (int s = beg; s < end; ++s) {
        int j = col[s];
        float w = dinv[j];
        const float* hj = hin + (size_t)j * D;
        a0 += w * hj[lane];
        if (lane + 64 < D)  a1 += w * hj[lane + 64];
        if (lane + 128 < D) a2 += w * hj[lane + 128];
    }
    float di = dinv[node];
    float* ho = hout + (size_t)node * D;
    ho[lane] = di * a0;
    if (lane + 64 < D)  ho[lane + 64]  = di * a1;
    if (lane + 128 < D) ho[lane + 128] = di * a2;
}

// ---------------- GEMM: Y[N,Fout] = X[N,Fin] @ W[Fin,Fout] + b ----------------
// block (64,4): 64 cols x 4 row-groups; each thread does 8 rows
__global__ void k_gemm(const float* __restrict__ X, const float* __restrict__ W,
                       const float* __restrict__ bias, float* __restrict__ Y,
                       int Fin, int Fout) {
    int col = blockIdx.x * 64 + threadIdx.x;
    size_t row0 = ((size_t)blockIdx.y * 4 + threadIdx.y) * 8;
    if (col >= Fout) return;
    float acc[8] = {0, 0, 0, 0, 0, 0, 0, 0};
    const float* xr = X + row0 * Fin;
    for (int k = 0; k < Fin; ++k) {
        float w = W[(size_t)k * Fout + col];
#pragma unroll
        for (int r = 0; r < 8; ++r) acc[r] += xr[(size_t)r * Fin + k] * w;
    }
    float bv = bias[col];
    float* yr = Y + row0 * Fout + col;
#pragma unroll
    for (int r = 0; r < 8; ++r) yr[(size_t)r * Fout] = acc[r] + bv;
}

// final GEMM: 138 -> 128, writes padded [NGRAPH, 45, 128] layout
__global__ void k_gemm_out(const float* __restrict__ X, const float* __restrict__ W,
                           const float* __restrict__ bias, float* __restrict__ out) {
    int col = blockIdx.x * 64 + threadIdx.x;   // < 128 always (grid.x = 2)
    size_t row0 = ((size_t)blockIdx.y * 4 + threadIdx.y) * 8;
    float acc[8] = {0, 0, 0, 0, 0, 0, 0, 0};
    const float* xr = X + row0 * (size_t)F_MID;
    for (int k = 0; k < F_MID; ++k) {
        float w = W[(size_t)k * F_OUT + col];
#pragma unroll
        for (int r = 0; r < 8; ++r) acc[r] += xr[(size_t)r * F_MID + k] * w;
    }
    float bv = bias[col];
#pragma unroll
    for (int r = 0; r < 8; ++r) {
        size_t i = row0 + r;
        size_t o = ((i >> 5) * PADR + (i & 31)) * (size_t)F_OUT + col;
        out[o] = acc[r] + bv;
    }
}

__global__ void k_padzero(float* __restrict__ out) {
    size_t idx = (size_t)blockIdx.x * 256 + threadIdx.x;
    const size_t total = (size_t)NGRAPH * (PADR - GSZ) * F_OUT;
    if (idx < total) {
        size_t b  = idx / ((PADR - GSZ) * F_OUT);
        int rem   = (int)(idx % ((PADR - GSZ) * F_OUT));
        int r     = GSZ + rem / F_OUT;
        int d     = rem % F_OUT;
        out[((size_t)b * PADR + r) * (size_t)F_OUT + d] = 0.f;
    }
}

// ---------------- launch ----------------

static inline size_t align256(size_t x) { return (x + 255) & ~(size_t)255; }

extern "C" void kernel_launch(void* const* d_in, const int* in_sizes, int n_in,
                              void* d_out, int out_size, void* d_ws, size_t ws_size,
                              hipStream_t stream) {
    const float* x   = (const float*)d_in[0];
    const int* ei    = (const int*)d_in[1];
    const int* src   = ei;            // edge_index[0]
    const int* dst   = ei + NE;       // edge_index[1]
    const float* W1  = (const float*)d_in[2];
    const float* b1  = (const float*)d_in[3];
    const float* W2  = (const float*)d_in[4];
    const float* b2  = (const float*)d_in[5];
    const float* W3  = (const float*)d_in[6];
    const float* b3  = (const float*)d_in[7];
    const float* W4  = (const float*)d_in[8];
    const float* b4  = (const float*)d_in[9];

    // workspace layout
    char* p = (char*)d_ws;
    float* bufW = (float*)p;            p += align256((size_t)NN * F_MID * sizeof(float));
    int* cnt    = (int*)p;              p += align256((size_t)NN * sizeof(int));
    int* rp     = (int*)p;              p += align256(((size_t)NN + 1) * sizeof(int));
    int* cursor = (int*)p;              p += align256((size_t)NN * sizeof(int));
    int* colix  = (int*)p;              p += align256((size_t)(NN + NE) * sizeof(int));
    float* dinv = (float*)p;            p += align256((size_t)NN * sizeof(float));
    int* bsum   = (int*)p;              p += align256(512 * sizeof(int));
    (void)ws_size; (void)n_in; (void)in_sizes; (void)out_size;

    float* S = (float*)d_out;           // first N*138 floats of d_out as scratch

    // ---- build CSR + dinv ----
    k_init_cnt<<<NN / 256, 256, 0, stream>>>(cnt);
    k_count<<<NE / 256, 256, 0, stream>>>(dst, cnt);
    k_scan1<<<NN / 1024, 256, 0, stream>>>(cnt, rp, bsum);
    k_scan2<<<1, 512, 0, stream>>>(bsum);
    k_scan3<<<NN / 256, 256, 0, stream>>>(rp, bsum, cursor);
    k_dinv<<<NN / 256, 256, 0, stream>>>(cnt, dinv);
    k_fill_self<<<NN / 256, 256, 0, stream>>>(cursor, colix);
    k_fill_edges<<<NE / 256, 256, 0, stream>>>(src, dst, cursor, colix);

    const int aggBlocks = NN / 4;      // 4 waves (nodes) per 256-thread block

    // ---- layer 1: g0 = A x (79) -> bufW ; h1 = g0 W1 + b1 -> S ----
    k_agg<<<aggBlocks, 256, 0, stream>>>(x, bufW, rp, colix, dinv, F_IN);
    {
        dim3 g((F_MID + 63) / 64, NN / 32), b(64, 4);
        k_gemm<<<g, b, 0, stream>>>(bufW, W1, b1, S, F_IN, F_MID);
    }
    // ---- layer 2 ----
    k_agg<<<aggBlocks, 256, 0, stream>>>(S, bufW, rp, colix, dinv, F_MID);
    {
        dim3 g((F_MID + 63) / 64, NN / 32), b(64, 4);
        k_gemm<<<g, b, 0, stream>>>(bufW, W2, b2, S, F_MID, F_MID);
    }
    // ---- layer 3 ----
    k_agg<<<aggBlocks, 256, 0, stream>>>(S, bufW, rp, colix, dinv, F_MID);
    {
        dim3 g((F_MID + 63) / 64, NN / 32), b(64, 4);
        k_gemm<<<g, b, 0, stream>>>(bufW, W3, b3, S, F_MID, F_MID);
    }
    // ---- layer 4: g3 = A h3 -> bufW ; out = g3 W4 + b4 -> padded d_out ----
    k_agg<<<aggBlocks, 256, 0, stream>>>(S, bufW, rp, colix, dinv, F_MID);
    {
        dim3 g(F_OUT / 64, NN / 32), b(64, 4);
        k_gemm_out<<<g, b, 0, stream>>>(bufW, W4, b4, (float*)d_out);
    }
    // zero the pad rows (after last read of S-scratch)
    {
        size_t total = (size_t)NGRAPH * (PADR - GSZ) * F_OUT;
        k_padzero<<<(unsigned)((total + 255) / 256), 256, 0, stream>>>((float*)d_out);
    }
}

// Round 2
// 3438.847 us; speedup vs baseline: 2.5612x; 2.5612x over previous
//
#include <hip/hip_runtime.h>

#define NN      524288      // nodes
#define NE      2097152     // edges
#define NGRAPH  16384
#define GSZ     32
#define PADR    45
#define F_IN    79
#define F_MID   138
#define F_OUT   128

typedef __attribute__((ext_vector_type(8))) short short8;
typedef __attribute__((ext_vector_type(4))) float f32x4;

__device__ __forceinline__ unsigned short f2b(float f) {
    union { float f; unsigned u; } v; v.f = f;
    unsigned r = v.u + 0x7FFF + ((v.u >> 16) & 1);   // RNE
    return (unsigned short)(r >> 16);
}

// ---------------- degree / CSR build ----------------

__global__ void k_init_cnt(int* __restrict__ cnt) {
    int i = blockIdx.x * 256 + threadIdx.x;
    if (i < NN) cnt[i] = 1;                      // self loop
}

__global__ void k_count(const int* __restrict__ dst, int* __restrict__ cnt) {
    int e = blockIdx.x * 256 + threadIdx.x;
    if (e < NE) atomicAdd(&cnt[dst[e]], 1);
}

__global__ void k_scan1(const int* __restrict__ cnt, int* __restrict__ rp,
                        int* __restrict__ bsum) {
    __shared__ int s[256];
    int tid = threadIdx.x;
    size_t base = (size_t)blockIdx.x * 1024 + (size_t)tid * 4;
    int c0 = cnt[base + 0], c1 = cnt[base + 1], c2 = cnt[base + 2], c3 = cnt[base + 3];
    int tsum = c0 + c1 + c2 + c3;
    s[tid] = tsum;
    __syncthreads();
    for (int off = 1; off < 256; off <<= 1) {
        int t = (tid >= off) ? s[tid - off] : 0;
        __syncthreads();
        s[tid] += t;
        __syncthreads();
    }
    int incl = s[tid];
    int ex = incl - tsum;
    rp[base + 0] = ex;
    rp[base + 1] = ex + c0;
    rp[base + 2] = ex + c0 + c1;
    rp[base + 3] = ex + c0 + c1 + c2;
    if (tid == 255) bsum[blockIdx.x] = incl;
}

__global__ void k_scan2(int* __restrict__ bsum) {
    __shared__ int s[512];
    int tid = threadIdx.x;
    int v = bsum[tid];
    s[tid] = v;
    __syncthreads();
    for (int off = 1; off < 512; off <<= 1) {
        int t = (tid >= off) ? s[tid - off] : 0;
        __syncthreads();
        s[tid] += t;
        __syncthreads();
    }
    bsum[tid] = s[tid] - v;                      // exclusive
}

__global__ void k_scan3(int* __restrict__ rp, const int* __restrict__ bsum,
                        int* __restrict__ cursor) {
    int i = blockIdx.x * 256 + threadIdx.x;
    if (i < NN) {
        int v = rp[i] + bsum[i >> 10];
        rp[i] = v;
        cursor[i] = v;
        if (i == 0) rp[NN] = NN + NE;
    }
}

__global__ void k_dinv(const int* __restrict__ cnt, float* __restrict__ dinv) {
    int i = blockIdx.x * 256 + threadIdx.x;
    if (i < NN) dinv[i] = rsqrtf((float)cnt[i]);
}

__global__ void k_fill_self(int* __restrict__ cursor, int* __restrict__ col) {
    int i = blockIdx.x * 256 + threadIdx.x;
    if (i < NN) { int s = atomicAdd(&cursor[i], 1); col[s] = i; }
}

__global__ void k_fill_edges(const int* __restrict__ src, const int* __restrict__ dst,
                             int* __restrict__ cursor, int* __restrict__ col) {
    int e = blockIdx.x * 256 + threadIdx.x;
    if (e < NE) { int s = atomicAdd(&cursor[dst[e]], 1); col[s] = src[e]; }
}

// ---------------- W -> W^T bf16, padded [ROWS][LDK] ----------------
__global__ void k_wconv(const float* __restrict__ W, unsigned short* __restrict__ WT,
                        int Fin, int Fout, int LDK) {
    int c = blockIdx.x;          // output col (row of WT)
    int k = threadIdx.x;         // k index
    float v = (k < Fin && c < Fout) ? W[(size_t)k * Fout + c] : 0.f;
    WT[(size_t)c * LDK + k] = f2b(v);
}

// ---------------- aggregation: G[i] = bf16( dinv[i] * sum_j dinv[j]*h[j] ) ----------------
// one wave per node; output bf16 row padded to LDK cols
__global__ void k_agg(const float* __restrict__ hin, unsigned short* __restrict__ gout,
                      const int* __restrict__ rp, const int* __restrict__ col,
                      const float* __restrict__ dinv, int D, int SIN, int LDK) {
    int gid  = blockIdx.x * blockDim.x + threadIdx.x;
    int node = gid >> 6;
    int lane = threadIdx.x & 63;
    if (node >= NN) return;
    int beg = rp[node], end = rp[node + 1];
    float a0 = 0.f, a1 = 0.f, a2 = 0.f;
    for (int s = beg; s < end; ++s) {
        int j = col[s];
        float w = dinv[j];
        const float* hj = hin + (size_t)j * SIN;
        if (lane < D)        a0 += w * hj[lane];
        if (lane + 64 < D)   a1 += w * hj[lane + 64];
        if (lane + 128 < D)  a2 += w * hj[lane + 128];
    }
    float di = dinv[node];
    unsigned short* go = gout + (size_t)node * LDK;
    go[lane] = (lane < D) ? f2b(di * a0) : 0;
    if (lane + 64 < LDK)  go[lane + 64]  = (lane + 64 < D)  ? f2b(di * a1) : 0;
    if (lane + 128 < LDK) go[lane + 128] = (lane + 128 < D) ? f2b(di * a2) : 0;
}

// ---------------- MFMA GEMM: Y[N,Fout] = G[N,LDK]bf16 @ WT^T + b ----------------
// block = 512 thr (8 waves), 128 rows/block (16 rows/wave); W entirely in LDS.
// A fragments load global->VGPR directly.
template<int LDK, int NT, bool PADOUT>
__global__ __launch_bounds__(512) void
k_mm(const unsigned short* __restrict__ G, const unsigned short* __restrict__ WT,
     const float* __restrict__ bias, float* __restrict__ Y, int Fout) {
    constexpr int KSTEPS = LDK / 32;
    constexpr int LDP = LDK + 8;                 // padded LDS stride (2-way only)
    constexpr int WROWS = NT * 16;
    __shared__ __align__(16) unsigned short Ws[WROWS * LDP];

    const int tid = threadIdx.x;
    // ---- cooperative load of W^T into LDS (16B chunks) ----
    constexpr int CW = WROWS * LDK / 8;
    for (int i = tid; i < CW; i += 512) {
        int r = i / (LDK / 8), cc = i % (LDK / 8);
        *(f32x4*)&Ws[r * LDP + cc * 8] = *(const f32x4*)&WT[(size_t)r * LDK + cc * 8];
    }
    __syncthreads();

    const int wv = tid >> 6, lane = tid & 63;
    const int lrow = lane & 15, lk = (lane >> 4) * 8;
    const size_t grow = (size_t)blockIdx.x * 128 + wv * 16 + lrow;

    // ---- A fragments: direct global loads, one short8 per K-step ----
    short8 a[KSTEPS];
#pragma unroll
    for (int ks = 0; ks < KSTEPS; ++ks)
        a[ks] = *(const short8*)&G[grow * LDK + ks * 32 + lk];

    f32x4 acc[NT];
#pragma unroll
    for (int n = 0; n < NT; ++n) acc[n] = (f32x4){0.f, 0.f, 0.f, 0.f};

#pragma unroll
    for (int ks = 0; ks < KSTEPS; ++ks) {
#pragma unroll
        for (int n = 0; n < NT; ++n) {
            short8 b = *(const short8*)&Ws[(n * 16 + lrow) * LDP + ks * 32 + lk];
            acc[n] = __builtin_amdgcn_mfma_f32_16x16x32_bf16(a[ks], b, acc[n], 0, 0, 0);
        }
    }

    // ---- epilogue: C/D layout col=lane&15, row=(lane>>4)*4+j ----
    const size_t row0 = (size_t)blockIdx.x * 128 + wv * 16 + (lane >> 4) * 4;
#pragma unroll
    for (int n = 0; n < NT; ++n) {
        int c = n * 16 + lrow;
        if (c >= Fout) continue;
        float bv = bias[c];
#pragma unroll
        for (int j = 0; j < 4; ++j) {
            size_t r = row0 + j;
            if (PADOUT) {
                size_t o = ((r >> 5) * PADR + (r & 31)) * (size_t)F_OUT + c;
                Y[o] = acc[n][j] + bv;
            } else {
                Y[r * (size_t)F_MID + c] = acc[n][j] + bv;
            }
        }
    }
}

__global__ void k_padzero(float* __restrict__ out) {
    size_t idx = (size_t)blockIdx.x * 256 + threadIdx.x;
    const size_t total = (size_t)NGRAPH * (PADR - GSZ) * F_OUT;
    if (idx < total) {
        size_t b  = idx / ((PADR - GSZ) * F_OUT);
        int rem   = (int)(idx % ((PADR - GSZ) * F_OUT));
        int r     = GSZ + rem / F_OUT;
        int d     = rem % F_OUT;
        out[((size_t)b * PADR + r) * (size_t)F_OUT + d] = 0.f;
    }
}

// ---------------- launch ----------------

static inline size_t align256(size_t x) { return (x + 255) & ~(size_t)255; }

extern "C" void kernel_launch(void* const* d_in, const int* in_sizes, int n_in,
                              void* d_out, int out_size, void* d_ws, size_t ws_size,
                              hipStream_t stream) {
    const float* x   = (const float*)d_in[0];
    const int* ei    = (const int*)d_in[1];
    const int* src   = ei;            // edge_index[0]
    const int* dst   = ei + NE;       // edge_index[1]
    const float* W1  = (const float*)d_in[2];
    const float* b1  = (const float*)d_in[3];
    const float* W2  = (const float*)d_in[4];
    const float* b2  = (const float*)d_in[5];
    const float* W3  = (const float*)d_in[6];
    const float* b3  = (const float*)d_in[7];
    const float* W4  = (const float*)d_in[8];
    const float* b4  = (const float*)d_in[9];

    // workspace layout
    char* p = (char*)d_ws;
    unsigned short* Gb = (unsigned short*)p;  p += align256((size_t)NN * 160 * 2);
    int* cnt    = (int*)p;              p += align256((size_t)NN * sizeof(int));
    int* rp     = (int*)p;              p += align256(((size_t)NN + 1) * sizeof(int));
    int* cursor = (int*)p;              p += align256((size_t)NN * sizeof(int));
    int* colix  = (int*)p;              p += align256((size_t)(NN + NE) * sizeof(int));
    float* dinv = (float*)p;            p += align256((size_t)NN * sizeof(float));
    int* bsum   = (int*)p;              p += align256(512 * sizeof(int));
    unsigned short* WT1 = (unsigned short*)p; p += align256(144 * 96 * 2);
    unsigned short* WT2 = (unsigned short*)p; p += align256(144 * 160 * 2);
    unsigned short* WT3 = (unsigned short*)p; p += align256(144 * 160 * 2);
    unsigned short* WT4 = (unsigned short*)p; p += align256(128 * 160 * 2);
    (void)ws_size; (void)n_in; (void)in_sizes; (void)out_size;

    float* S = (float*)d_out;           // first N*138 floats of d_out as fp32 scratch

    // ---- build CSR + dinv ----
    k_init_cnt<<<NN / 256, 256, 0, stream>>>(cnt);
    k_count<<<NE / 256, 256, 0, stream>>>(dst, cnt);
    k_scan1<<<NN / 1024, 256, 0, stream>>>(cnt, rp, bsum);
    k_scan2<<<1, 512, 0, stream>>>(bsum);
    k_scan3<<<NN / 256, 256, 0, stream>>>(rp, bsum, cursor);
    k_dinv<<<NN / 256, 256, 0, stream>>>(cnt, dinv);
    k_fill_self<<<NN / 256, 256, 0, stream>>>(cursor, colix);
    k_fill_edges<<<NE / 256, 256, 0, stream>>>(src, dst, cursor, colix);

    // ---- W -> bf16 transposed/padded ----
    k_wconv<<<144, 96, 0, stream>>>(W1, WT1, F_IN, F_MID, 96);
    k_wconv<<<144, 160, 0, stream>>>(W2, WT2, F_MID, F_MID, 160);
    k_wconv<<<144, 160, 0, stream>>>(W3, WT3, F_MID, F_MID, 160);
    k_wconv<<<128, 160, 0, stream>>>(W4, WT4, F_MID, F_OUT, 160);

    const int aggBlocks = NN / 4;      // 4 waves (nodes) per 256-thread block
    const int mmBlocks  = NN / 128;

    // ---- layer 1 ----
    k_agg<<<aggBlocks, 256, 0, stream>>>(x, Gb, rp, colix, dinv, F_IN, F_IN, 96);
    k_mm<96, 9, false><<<mmBlocks, 512, 0, stream>>>(Gb, WT1, b1, S, F_MID);
    // ---- layer 2 ----
    k_agg<<<aggBlocks, 256, 0, stream>>>(S, Gb, rp, colix, dinv, F_MID, F_MID, 160);
    k_mm<160, 9, false><<<mmBlocks, 512, 0, stream>>>(Gb, WT2, b2, S, F_MID);
    // ---- layer 3 ----
    k_agg<<<aggBlocks, 256, 0, stream>>>(S, Gb, rp, colix, dinv, F_MID, F_MID, 160);
    k_mm<160, 9, false><<<mmBlocks, 512, 0, stream>>>(Gb, WT3, b3, S, F_MID);
    // ---- layer 4 (padded output) ----
    k_agg<<<aggBlocks, 256, 0, stream>>>(S, Gb, rp, colix, dinv, F_MID, F_MID, 160);
    k_mm<160, 8, true><<<mmBlocks, 512, 0, stream>>>(Gb, WT4, b4, (float*)d_out, F_OUT);
    // ---- zero pad rows ----
    {
        size_t total = (size_t)NGRAPH * (PADR - GSZ) * F_OUT;
        k_padzero<<<(unsigned)((total + 255) / 256), 256, 0, stream>>>((float*)d_out);
    }
}

// Round 3
// 1233.847 us; speedup vs baseline: 7.1382x; 2.7871x over previous
//
#include <hip/hip_runtime.h>

#define NN      524288      // nodes
#define NE      2097152     // edges
#define NGRAPH  16384
#define GSZ     32
#define PADR    45
#define F_IN    79
#define F_MID   138
#define F_OUT   128

typedef __attribute__((ext_vector_type(8))) short short8;
typedef __attribute__((ext_vector_type(4))) float f32x4;

__device__ __forceinline__ unsigned short f2b(float f) {
    union { float f; unsigned u; } v; v.f = f;
    unsigned r = v.u + 0x7FFF + ((v.u >> 16) & 1);   // RNE
    return (unsigned short)(r >> 16);
}
__device__ __forceinline__ float b2f(unsigned short u) {
    union { unsigned u; float f; } v; v.u = ((unsigned)u) << 16;
    return v.f;
}

// ---------------- degree / CSR build ----------------

__global__ void k_init_cnt(int* __restrict__ cnt) {
    int i = blockIdx.x * 256 + threadIdx.x;
    if (i < NN) cnt[i] = 1;                      // self loop
}

__global__ void k_count(const int* __restrict__ dst, int* __restrict__ cnt) {
    int e = blockIdx.x * 256 + threadIdx.x;
    if (e < NE) atomicAdd(&cnt[dst[e]], 1);
}

__global__ void k_scan1(const int* __restrict__ cnt, int* __restrict__ rp,
                        int* __restrict__ bsum) {
    __shared__ int s[256];
    int tid = threadIdx.x;
    size_t base = (size_t)blockIdx.x * 1024 + (size_t)tid * 4;
    int c0 = cnt[base + 0], c1 = cnt[base + 1], c2 = cnt[base + 2], c3 = cnt[base + 3];
    int tsum = c0 + c1 + c2 + c3;
    s[tid] = tsum;
    __syncthreads();
    for (int off = 1; off < 256; off <<= 1) {
        int t = (tid >= off) ? s[tid - off] : 0;
        __syncthreads();
        s[tid] += t;
        __syncthreads();
    }
    int incl = s[tid];
    int ex = incl - tsum;
    rp[base + 0] = ex;
    rp[base + 1] = ex + c0;
    rp[base + 2] = ex + c0 + c1;
    rp[base + 3] = ex + c0 + c1 + c2;
    if (tid == 255) bsum[blockIdx.x] = incl;
}

__global__ void k_scan2(int* __restrict__ bsum) {
    __shared__ int s[512];
    int tid = threadIdx.x;
    int v = bsum[tid];
    s[tid] = v;
    __syncthreads();
    for (int off = 1; off < 512; off <<= 1) {
        int t = (tid >= off) ? s[tid - off] : 0;
        __syncthreads();
        s[tid] += t;
        __syncthreads();
    }
    bsum[tid] = s[tid] - v;                      // exclusive
}

__global__ void k_scan3(int* __restrict__ rp, const int* __restrict__ bsum,
                        int* __restrict__ cursor) {
    int i = blockIdx.x * 256 + threadIdx.x;
    if (i < NN) {
        int v = rp[i] + bsum[i >> 10];
        rp[i] = v;
        cursor[i] = v;
        if (i == 0) rp[NN] = NN + NE;
    }
}

__global__ void k_dinv(const int* __restrict__ cnt, float* __restrict__ dinv) {
    int i = blockIdx.x * 256 + threadIdx.x;
    if (i < NN) dinv[i] = rsqrtf((float)cnt[i]);
}

__global__ void k_fill_self(int* __restrict__ cursor, int* __restrict__ col) {
    int i = blockIdx.x * 256 + threadIdx.x;
    if (i < NN) { int s = atomicAdd(&cursor[i], 1); col[s] = i; }
}

__global__ void k_fill_edges(const int* __restrict__ src, const int* __restrict__ dst,
                             int* __restrict__ cursor, int* __restrict__ col) {
    int e = blockIdx.x * 256 + threadIdx.x;
    if (e < NE) { int s = atomicAdd(&cursor[dst[e]], 1); col[s] = src[e]; }
}

// ---------------- weight / bias / input prep ----------------

// WT[c][k] = bf16(W[k][c]), zero-padded to [WROWS][LDK]
__global__ void k_wconv(const float* __restrict__ W, unsigned short* __restrict__ WT,
                        int Fin, int Fout, int LDK) {
    int c = blockIdx.x;
    int k = threadIdx.x;
    float v = (k < Fin && c < Fout) ? W[(size_t)k * Fout + c] : 0.f;
    WT[(size_t)c * LDK + k] = f2b(v);
}

__global__ void k_bpad(const float* __restrict__ b, float* __restrict__ bp, int Fout) {
    int i = threadIdx.x;
    bp[i] = (i < Fout) ? b[i] : 0.f;
}

// Xp[n][c] = bf16(dinv[n] * x[n][c]) zero-padded to 96 cols
__global__ void k_xconv(const float* __restrict__ x, const float* __restrict__ dinv,
                        unsigned short* __restrict__ Xp) {
    int n = blockIdx.x * 4 + threadIdx.y;
    int c = threadIdx.x;            // 0..95
    float v = (c < F_IN) ? dinv[n] * x[(size_t)n * F_IN + c] : 0.f;
    Xp[(size_t)n * 96 + c] = f2b(v);
}

// ---------------- fused layer: gather-aggregate + MFMA GEMM ----------------
// Hin: bf16 [N][LDKIN], rows pre-scaled by dinv[src].
// out row i = sum_{j in N(i)} Hin[j]  -> * dinv[i] -> bf16 A-frag -> @ W + b
// MODE 0: write bf16 prescaled Hout [N][LDKOUT];  MODE 1: fp32 padded d_out.
template<int LDKIN, int LDKOUT, int NT, int MODE>
__global__ __launch_bounds__(512) void
k_fused(const unsigned short* __restrict__ Hin, const unsigned short* __restrict__ WT,
        const float* __restrict__ bias, void* __restrict__ Yout,
        const int* __restrict__ rp, const int* __restrict__ col,
        const float* __restrict__ dinv) {
    constexpr int KSTEPS = LDKIN / 32;
    constexpr int LDP = LDKIN + 8;               // pad -> 2-way LDS conflicts only
    constexpr int WROWS = NT * 16;
    __shared__ __align__(16) unsigned short Ws[WROWS * LDP];

    const int tid = threadIdx.x;
    // cooperative W^T -> LDS
    constexpr int CW = WROWS * LDKIN / 8;
    for (int i = tid; i < CW; i += 512) {
        int r = i / (LDKIN / 8), cc = i % (LDKIN / 8);
        *(f32x4*)&Ws[r * LDP + cc * 8] = *(const f32x4*)&WT[(size_t)r * LDKIN + cc * 8];
    }

    const int wv = tid >> 6, lane = tid & 63;
    const int lrow = lane & 15, kg = lane >> 4, lk = kg * 8;
    const int row = blockIdx.x * 128 + wv * 16 + lrow;

    const int beg = rp[row], end = rp[row + 1];
    const float di = dinv[row];

    // ---- gather-aggregate this row's A-slice in fp32 ----
    float acc[KSTEPS][8] = {};
    for (int s = beg; s < end; ++s) {
        int j = col[s];
        const unsigned short* hj = Hin + (size_t)j * LDKIN + lk;
#pragma unroll
        for (int ks = 0; ks < KSTEPS; ++ks) {
            short8 v = *(const short8*)(hj + ks * 32);
#pragma unroll
            for (int e = 0; e < 8; ++e)
                acc[ks][e] += b2f((unsigned short)v[e]);
        }
    }

    // ---- to bf16 A fragments ----
    short8 a[KSTEPS];
#pragma unroll
    for (int ks = 0; ks < KSTEPS; ++ks)
#pragma unroll
        for (int e = 0; e < 8; ++e)
            a[ks][e] = (short)f2b(di * acc[ks][e]);

    __syncthreads();                              // Ws ready

    f32x4 acc2[NT];
#pragma unroll
    for (int n = 0; n < NT; ++n) acc2[n] = (f32x4){0.f, 0.f, 0.f, 0.f};

#pragma unroll
    for (int ks = 0; ks < KSTEPS; ++ks) {
#pragma unroll
        for (int n = 0; n < NT; ++n) {
            short8 b = *(const short8*)&Ws[(n * 16 + lrow) * LDP + ks * 32 + lk];
            acc2[n] = __builtin_amdgcn_mfma_f32_16x16x32_bf16(a[ks], b, acc2[n], 0, 0, 0);
        }
    }

    // ---- epilogue: C/D layout col=lane&15, row=(lane>>4)*4+j ----
    const size_t row0 = (size_t)blockIdx.x * 128 + wv * 16 + kg * 4;
    if (MODE == 0) {
        float d4[4];
#pragma unroll
        for (int j = 0; j < 4; ++j) d4[j] = dinv[row0 + j];
        unsigned short* Yp = (unsigned short*)Yout;
#pragma unroll
        for (int n = 0; n < NT; ++n) {
            int c = n * 16 + lrow;
            float bv = bias[c];
#pragma unroll
            for (int j = 0; j < 4; ++j) {
                size_t r = row0 + j;
                Yp[r * LDKOUT + c] = f2b(d4[j] * (acc2[n][j] + bv));
            }
        }
    } else {
        float* Yo = (float*)Yout;
#pragma unroll
        for (int n = 0; n < NT; ++n) {
            int c = n * 16 + lrow;
            float bv = bias[c];
#pragma unroll
            for (int j = 0; j < 4; ++j) {
                size_t r = row0 + j;
                size_t o = ((r >> 5) * PADR + (r & 31)) * (size_t)F_OUT + c;
                Yo[o] = acc2[n][j] + bv;
            }
        }
    }
}

__global__ void k_padzero(float* __restrict__ out) {
    size_t idx = (size_t)blockIdx.x * 256 + threadIdx.x;
    const size_t total = (size_t)NGRAPH * (PADR - GSZ) * F_OUT;
    if (idx < total) {
        size_t b  = idx / ((PADR - GSZ) * F_OUT);
        int rem   = (int)(idx % ((PADR - GSZ) * F_OUT));
        int r     = GSZ + rem / F_OUT;
        int d     = rem % F_OUT;
        out[((size_t)b * PADR + r) * (size_t)F_OUT + d] = 0.f;
    }
}

// ---------------- launch ----------------

static inline size_t align256(size_t x) { return (x + 255) & ~(size_t)255; }

extern "C" void kernel_launch(void* const* d_in, const int* in_sizes, int n_in,
                              void* d_out, int out_size, void* d_ws, size_t ws_size,
                              hipStream_t stream) {
    const float* x   = (const float*)d_in[0];
    const int* ei    = (const int*)d_in[1];
    const int* src   = ei;            // edge_index[0]
    const int* dst   = ei + NE;       // edge_index[1]
    const float* W1  = (const float*)d_in[2];
    const float* b1  = (const float*)d_in[3];
    const float* W2  = (const float*)d_in[4];
    const float* b2  = (const float*)d_in[5];
    const float* W3  = (const float*)d_in[6];
    const float* b3  = (const float*)d_in[7];
    const float* W4  = (const float*)d_in[8];
    const float* b4  = (const float*)d_in[9];

    // workspace layout
    char* p = (char*)d_ws;
    unsigned short* HA = (unsigned short*)p;  p += align256((size_t)NN * 160 * 2); // ping
    unsigned short* HB = (unsigned short*)p;  p += align256((size_t)NN * 160 * 2); // pong
    int* cnt    = (int*)p;              p += align256((size_t)NN * sizeof(int));
    int* rp     = (int*)p;              p += align256(((size_t)NN + 1) * sizeof(int));
    int* cursor = (int*)p;              p += align256((size_t)NN * sizeof(int));
    int* colix  = (int*)p;              p += align256((size_t)(NN + NE) * sizeof(int));
    float* dinv = (float*)p;            p += align256((size_t)NN * sizeof(float));
    int* bsum   = (int*)p;              p += align256(512 * sizeof(int));
    unsigned short* WT1 = (unsigned short*)p; p += align256(160 * 96 * 2);
    unsigned short* WT2 = (unsigned short*)p; p += align256(160 * 160 * 2);
    unsigned short* WT3 = (unsigned short*)p; p += align256(160 * 160 * 2);
    unsigned short* WT4 = (unsigned short*)p; p += align256(128 * 160 * 2);
    float* bp1 = (float*)p;             p += align256(160 * sizeof(float));
    float* bp2 = (float*)p;             p += align256(160 * sizeof(float));
    float* bp3 = (float*)p;             p += align256(160 * sizeof(float));
    (void)ws_size; (void)n_in; (void)in_sizes; (void)out_size;

    // ---- build CSR + dinv ----
    k_init_cnt<<<NN / 256, 256, 0, stream>>>(cnt);
    k_count<<<NE / 256, 256, 0, stream>>>(dst, cnt);
    k_scan1<<<NN / 1024, 256, 0, stream>>>(cnt, rp, bsum);
    k_scan2<<<1, 512, 0, stream>>>(bsum);
    k_scan3<<<NN / 256, 256, 0, stream>>>(rp, bsum, cursor);
    k_dinv<<<NN / 256, 256, 0, stream>>>(cnt, dinv);
    k_fill_self<<<NN / 256, 256, 0, stream>>>(cursor, colix);
    k_fill_edges<<<NE / 256, 256, 0, stream>>>(src, dst, cursor, colix);

    // ---- weights/bias/input prep ----
    k_wconv<<<160, 96, 0, stream>>>(W1, WT1, F_IN, F_MID, 96);
    k_wconv<<<160, 160, 0, stream>>>(W2, WT2, F_MID, F_MID, 160);
    k_wconv<<<160, 160, 0, stream>>>(W3, WT3, F_MID, F_MID, 160);
    k_wconv<<<128, 160, 0, stream>>>(W4, WT4, F_MID, F_OUT, 160);
    k_bpad<<<1, 160, 0, stream>>>(b1, bp1, F_MID);
    k_bpad<<<1, 160, 0, stream>>>(b2, bp2, F_MID);
    k_bpad<<<1, 160, 0, stream>>>(b3, bp3, F_MID);
    {
        dim3 b(96, 4);
        k_xconv<<<NN / 4, b, 0, stream>>>(x, dinv, HA);   // bf16 prescaled x -> HA
    }

    const int blocks = NN / 128;   // 4096

    // layer 1: HA[96] -> HB[160]
    k_fused<96, 160, 10, 0><<<blocks, 512, 0, stream>>>(HA, WT1, bp1, HB, rp, colix, dinv);
    // layer 2: HB -> HA
    k_fused<160, 160, 10, 0><<<blocks, 512, 0, stream>>>(HB, WT2, bp2, HA, rp, colix, dinv);
    // layer 3: HA -> HB
    k_fused<160, 160, 10, 0><<<blocks, 512, 0, stream>>>(HA, WT3, bp3, HB, rp, colix, dinv);
    // layer 4: HB -> padded fp32 d_out
    k_fused<160, 160, 8, 1><<<blocks, 512, 0, stream>>>(HB, WT4, b4, d_out, rp, colix, dinv);
    // zero pad rows
    {
        size_t total = (size_t)NGRAPH * (PADR - GSZ) * F_OUT;
        k_padzero<<<(unsigned)((total + 255) / 256), 256, 0, stream>>>((float*)d_out);
    }
}